// Round 8
// baseline (243.006 us; speedup 1.0000x reference)
//
#include <hip/hip_runtime.h>
#include <hip/hip_cooperative_groups.h>

namespace cg = cooperative_groups;

// Problem constants (match reference setup_inputs).
#define BB 4
#define CC 128
#define CE 64
#define VV 4096
#define NLEV 14   // MAX_LEVELS
#define NNODE (BB * VV)      // 16384
#define GRID  (BB * CC)      // 512 blocks
#define WBLK  (GRID - BB)    // 508 weight blocks
#define NPB   33             // nodes per weight block (508*33 >= 16384)

// Workspace:
//   wsort [BB*VV] float : edge weight of node at SORTED position i
//   giInv [BB*VV] int   : levelpos of pixel v
//   cpl   [BB*VV] int2  : {cp (levelpos of parent), sorted idx i} at levelpos k
//   offs  [BB*16] int   : level start offsets

__device__ __forceinline__ void lds_fadd(float* p, float v) {
    unsafeAtomicAdd(p, v);   // ds_add_f32 on gfx950 LDS
}

// ---------------------------------------------------------------------------
// Single cooperative kernel.
//  Phase 1: blocks [0,BB)  : per-batch counting sort -> giInv/cpl/offs
//           blocks [BB,512): edge weights (33 nodes each, quad shuffle-reduce)
//  grid.sync()
//  Phase 2: all 512 blocks : per-(b,c) tree filter, fused {val,nrm} chain,
//           packed b32 {w_hi20, cp12}, 48 KB LDS re-aliased.
// ---------------------------------------------------------------------------
__global__ __launch_bounds__(256) void fused_kernel(
    const float* __restrict__ feat,
    const float* __restrict__ embed,
    const int*  __restrict__ sorted_index,
    const int*  __restrict__ sorted_parent,
    const int*  __restrict__ node_level,
    float* __restrict__ wsort,
    int*   __restrict__ giInv,
    int2*  __restrict__ cpl,
    int*   __restrict__ offs,
    float* __restrict__ out)
{
    __shared__ __align__(16) int lds[3 * VV];   // 48 KB, aliased per phase
    __shared__ int hist[NLEV + 1];
    __shared__ int cursor[NLEV];
    __shared__ int offSh[NLEV + 1];
    int tid = threadIdx.x;

    // ---------------- Phase 1 ----------------
    if (blockIdx.x < BB) {
        // counting sort for batch b
        int b = blockIdx.x;
        int* si_s  = lds;            // VV
        int* pos_s = lds + VV;       // VV
        int* lo_s  = lds + 2 * VV;   // VV
        const int* lev = node_level    + b * VV;
        const int* si  = sorted_index  + b * VV;
        const int* par = sorted_parent + b * VV;

        if (tid < NLEV + 1) hist[tid] = 0;
        __syncthreads();
        for (int i = tid; i < VV; i += 256) {
            si_s[i] = si[i];
            int d = lev[i]; d = d < NLEV - 1 ? d : NLEV - 1;
            atomicAdd(&hist[d], 1);
        }
        __syncthreads();
        if (tid == 0) {
            int acc = 0;
            for (int d = 0; d < NLEV; ++d) { int h = hist[d]; offSh[d] = acc; cursor[d] = acc; acc += h; }
            offSh[NLEV] = acc;
        }
        __syncthreads();
        if (tid <= NLEV) offs[b * 16 + tid] = offSh[tid];
        for (int i = tid; i < VV; i += 256) {
            int d = lev[i]; d = d < NLEV - 1 ? d : NLEV - 1;
            int k = atomicAdd(&cursor[d], 1);
            pos_s[i] = k;
            lo_s[k]  = i;
            giInv[b * VV + si_s[i]] = k;
        }
        __syncthreads();
        for (int k = tid; k < VV; k += 256) {
            int i = lo_s[k];
            cpl[b * VV + k] = make_int2(pos_s[par[i]], i);
        }
    } else {
        // edge weights: quad of lanes per node, 16 ce per lane
        int base = (blockIdx.x - BB) * NPB;
        int nl   = tid >> 2;          // local node 0..63 (use first 33)
        int ch   = tid & 3;           // ce chunk
        int g    = base + nl;         // global node id
        if (nl < NPB && g < NNODE) {
            int b = g >> 12;
            int i = g & (VV - 1);
            int vi = sorted_index[g];
            int p  = sorted_parent[g];
            int vp = sorted_index[b * VV + p];
            const float* eb = embed + (size_t)b * CE * VV;
            float acc = 0.f;
            #pragma unroll
            for (int r = 0; r < 16; ++r) {
                int ce = ch * 16 + r;
                float d = eb[ce * VV + vi] - eb[ce * VV + vp];
                acc = fmaf(d, d, acc);
            }
            acc += __shfl_xor(acc, 1, 64);
            acc += __shfl_xor(acc, 2, 64);
            if (ch == 0) wsort[g] = __expf(-acc);
        }
    }

    __threadfence();
    cg::this_grid().sync();

    // ---------------- Phase 2: tree filter ----------------
    float2* vv = (float2*)lds;        // 32 KB {val, nrm} by levelpos
    int*    cw = lds + 2 * VV;        // 16 KB packed {w_hi20, cp12}
    __shared__ int offS[16];
    int b = blockIdx.x >> 7;          // CC = 128
    int c = blockIdx.x & (CC - 1);

    const int2*  cplB = cpl   + b * VV;
    const int*   ivB  = giInv + b * VV;
    const float* wsB  = wsort + b * VV;
    const float* f    = feat + ((size_t)(b * CC + c)) * VV;

    if (tid < 16) offS[tid] = offs[b * 16 + tid];

    // stage + pack: coalesced int2 reads; w gather hits L1/L2 (16 KB/batch)
    #pragma unroll
    for (int t = 0; t < 16; ++t) {
        int k = tid + t * 256;
        int2 x = cplB[k];
        int wb = __float_as_int(wsB[x.y]);
        cw[k] = (wb & 0xFFFFF000) | x.x;
    }

    // init: coalesced float4/int4 reads, scattered b64 LDS writes; keep kk
    int4 kkR[4];
    #pragma unroll
    for (int t = 0; t < 4; ++t) {
        int idx = tid + t * 256;
        float4 fv = ((const float4*)f)[idx];
        int4   kk = ((const int4*)ivB)[idx];
        kkR[t] = kk;
        vv[kk.x] = make_float2(fv.x, 1.f);
        vv[kk.y] = make_float2(fv.y, 1.f);
        vv[kk.z] = make_float2(fv.z, 1.f);
        vv[kk.w] = make_float2(fv.w, 1.f);
    }
    __syncthreads();

    // upward: parents of level d are exactly level d-1 -> phase-safe atomics
    for (int d = NLEV - 1; d >= 1; --d) {
        int s = offS[d], e = offS[d + 1];
        if (s == e) continue;                 // offS uniform -> safe skip
        for (int k = s + tid; k < e; k += 256) {
            int x = cw[k];
            float w = __int_as_float(x & 0xFFFFF000);
            int  cp = x & 0xFFF;
            float2 u = vv[k];
            lds_fadd(&vv[cp].x, w * u.x);
            lds_fadd(&vv[cp].y, w * u.y);
        }
        __syncthreads();
    }

    // downward: in place; parent (level d-1) final before level d reads it
    for (int d = 1; d <= NLEV - 1; ++d) {
        int s = offS[d], e = offS[d + 1];
        if (s == e) continue;
        for (int k = s + tid; k < e; k += 256) {
            int x = cw[k];
            float w = __int_as_float(x & 0xFFFFF000);
            int  cp = x & 0xFFF;
            float2 u  = vv[k];
            float2 pa = vv[cp];
            vv[k] = make_float2(fmaf(w, fmaf(-w, u.x, pa.x), u.x),
                                fmaf(w, fmaf(-w, u.y, pa.y), u.y));
        }
        __syncthreads();
    }

    // epilogue: scattered b64 LDS reads, coalesced float4 stores
    float* ob = out + ((size_t)(b * CC + c)) * VV;
    #pragma unroll
    for (int t = 0; t < 4; ++t) {
        int idx = tid + t * 256;
        int4 kk = kkR[t];
        float2 u0 = vv[kk.x];
        float2 u1 = vv[kk.y];
        float2 u2 = vv[kk.z];
        float2 u3 = vv[kk.w];
        float4 r;
        r.x = __fdividef(u0.x, u0.y);
        r.y = __fdividef(u1.x, u1.y);
        r.z = __fdividef(u2.x, u2.y);
        r.w = __fdividef(u3.x, u3.y);
        ((float4*)ob)[idx] = r;
    }
}

extern "C" void kernel_launch(void* const* d_in, const int* in_sizes, int n_in,
                              void* d_out, int out_size, void* d_ws, size_t ws_size,
                              hipStream_t stream) {
    const float* feat          = (const float*)d_in[0];
    const float* embed         = (const float*)d_in[1];
    const int*   sorted_index  = (const int*)d_in[2];
    const int*   sorted_parent = (const int*)d_in[3];
    const int*   node_level    = (const int*)d_in[4];
    float* out = (float*)d_out;

    char* ws = (char*)d_ws;
    const size_t A = (size_t)BB * VV * 4;     // 64 KB
    float* wsort = (float*)(ws);              // 64 KB
    int*   giInv = (int*)  (ws + A);          // 64 KB
    int2*  cpl   = (int2*) (ws + 2 * A);      // 128 KB
    int*   offs  = (int*)  (ws + 4 * A);      // 256 B

    void* args[] = {
        (void*)&feat, (void*)&embed, (void*)&sorted_index, (void*)&sorted_parent,
        (void*)&node_level, (void*)&wsort, (void*)&giInv, (void*)&cpl,
        (void*)&offs, (void*)&out
    };
    hipLaunchCooperativeKernel((const void*)fused_kernel,
                               dim3(GRID), dim3(256), args, 0, stream);
}

// Round 9
// 110.294 us; speedup vs baseline: 2.2033x; 2.2033x over previous
//
#include <hip/hip_runtime.h>

// Problem constants (match reference setup_inputs).
#define BB 4
#define CC 128
#define CE 64
#define VV 4096
#define NLEV 14   // MAX_LEVELS

// Workspace:
//   wsort [BB*VV] float : edge weight of node at SORTED position i
//   giInv [BB*VV] int   : levelpos of pixel v
//   cpl   [BB*VV] int2  : {cp (levelpos of parent), sorted idx i} at levelpos k
//   offs  [BB*16] int   : level start offsets

__device__ __forceinline__ void lds_fadd(float* p, float v) {
    unsafeAtomicAdd(p, v);   // ds_add_f32 on gfx950 LDS
}

// ---------------------------------------------------------------------------
// K1 (fused): blocks [0,BB)           : per-batch counting sort -> tables
//             blocks [BB, BB+BB*64)   : edge weights in SORTED order
//             (independent of each other -> run concurrently in one launch)
// ---------------------------------------------------------------------------
__global__ __launch_bounds__(256) void prep_kernel(
    const float* __restrict__ embed,
    const int* __restrict__ sorted_index,
    const int* __restrict__ sorted_parent,
    const int* __restrict__ node_level,
    float* __restrict__ wsort,
    int*   __restrict__ giInv,
    int2*  __restrict__ cpl,
    int*   __restrict__ offs)
{
    int tid = threadIdx.x;
    if (blockIdx.x < BB) {
        int b = blockIdx.x;
        __shared__ int si_s[VV];
        __shared__ int pos_s[VV];
        __shared__ int lo_s[VV];
        __shared__ int hist[NLEV + 1];
        __shared__ int cursor[NLEV];
        __shared__ int offSh[NLEV + 1];
        const int* lev = node_level    + b * VV;
        const int* si  = sorted_index  + b * VV;
        const int* par = sorted_parent + b * VV;

        if (tid < NLEV + 1) hist[tid] = 0;
        __syncthreads();
        for (int i = tid; i < VV; i += 256) {
            si_s[i] = si[i];
            int d = lev[i]; d = d < NLEV - 1 ? d : NLEV - 1;
            atomicAdd(&hist[d], 1);
        }
        __syncthreads();
        if (tid == 0) {
            int acc = 0;
            for (int d = 0; d < NLEV; ++d) { int h = hist[d]; offSh[d] = acc; cursor[d] = acc; acc += h; }
            offSh[NLEV] = acc;
        }
        __syncthreads();
        if (tid <= NLEV) offs[b * 16 + tid] = offSh[tid];
        for (int i = tid; i < VV; i += 256) {
            int d = lev[i]; d = d < NLEV - 1 ? d : NLEV - 1;
            int k = atomicAdd(&cursor[d], 1);
            pos_s[i] = k;
            lo_s[k]  = i;
            giInv[b * VV + si_s[i]] = k;
        }
        __syncthreads();
        for (int k = tid; k < VV; k += 256) {
            int i = lo_s[k];
            cpl[b * VV + k] = make_int2(pos_s[par[i]], i);
        }
    } else {
        // weight: block = 64 nodes; wave w covers ce chunk [16w, 16w+16).
        __shared__ float part[4][64];
        int bb   = blockIdx.x - BB;
        int b    = bb >> 6;
        int n0   = (bb & 63) << 6;
        int lane = tid & 63;
        int w    = tid >> 6;
        int i    = n0 + lane;
        int vi = sorted_index[b * VV + i];
        int p  = sorted_parent[b * VV + i];
        int vp = sorted_index[b * VV + p];
        const float* eb = embed + (size_t)b * CE * VV;
        float acc = 0.f;
        #pragma unroll
        for (int r = 0; r < 16; ++r) {
            int ce = w * 16 + r;
            float d = eb[ce * VV + vi] - eb[ce * VV + vp];
            acc = fmaf(d, d, acc);
        }
        part[w][lane] = acc;
        __syncthreads();
        if (w == 0) {
            float d2 = part[0][lane] + part[1][lane] + part[2][lane] + part[3][lane];
            wsort[b * VV + i] = __expf(-d2);
        }
    }
}

// ---------------------------------------------------------------------------
// K2: tree filter, TWO channels per block + shared nrm chain. 256 blocks,
//     512 threads (8 waves/CU), 64 KB LDS. vs one-channel blocks: LDS atomic
//     total -25%, cw/giInv staging traffic -50%, nrm chains 128->64 per batch.
//     cw packs {w_hi20, cp12}; val & nrm use the SAME truncated w so the
//     final division cancels most of the perturbation.
// ---------------------------------------------------------------------------
__global__ __launch_bounds__(512) void tree2_kernel(
    const float* __restrict__ feat,
    const float* __restrict__ wsort,
    const int*  __restrict__ giInv,
    const int2* __restrict__ cpl,
    const int*  __restrict__ offs,
    float* __restrict__ out)
{
    __shared__ float val0[VV];   // 16 KB  channel c0 by levelpos
    __shared__ float val1[VV];   // 16 KB  channel c0+1
    __shared__ float nrm[VV];    // 16 KB  shared normalizer
    __shared__ int   cw[VV];     // 16 KB  packed {w_hi20, cp12}
    __shared__ int   offS[16];
    int b   = blockIdx.x >> 6;   // 64 channel-pairs per batch
    int c0  = (blockIdx.x & 63) << 1;
    int tid = threadIdx.x;

    const int2*  cplB = cpl   + b * VV;
    const int*   ivB  = giInv + b * VV;
    const float* wsB  = wsort + b * VV;
    const float* f0   = feat + ((size_t)(b * CC + c0)) * VV;
    const float* f1   = f0 + VV;

    if (tid < 16) offS[tid] = offs[b * 16 + tid];

    // stage + pack: coalesced int2 reads; w gather hits L1/L2 (16 KB/batch)
    #pragma unroll
    for (int t = 0; t < 8; ++t) {
        int k = tid + t * 512;
        int2 x = cplB[k];
        int wb = __float_as_int(wsB[x.y]);
        cw[k] = (wb & 0xFFFFF000) | x.x;
    }

    // init: coalesced float4/int4 reads, scattered b32 LDS writes; keep kk
    int4 kkR[2];
    #pragma unroll
    for (int t = 0; t < 2; ++t) {
        int idx = tid + t * 512;
        int4   kk = ((const int4*)ivB)[idx];
        float4 a  = ((const float4*)f0)[idx];
        float4 bq = ((const float4*)f1)[idx];
        kkR[t] = kk;
        val0[kk.x] = a.x;  val0[kk.y] = a.y;  val0[kk.z] = a.z;  val0[kk.w] = a.w;
        val1[kk.x] = bq.x; val1[kk.y] = bq.y; val1[kk.z] = bq.z; val1[kk.w] = bq.w;
        nrm[kk.x] = 1.f;   nrm[kk.y] = 1.f;   nrm[kk.z] = 1.f;   nrm[kk.w] = 1.f;
    }
    __syncthreads();

    // upward: parents of level d are exactly level d-1 -> phase-safe atomics
    for (int d = NLEV - 1; d >= 1; --d) {
        int s = offS[d], e = offS[d + 1];
        if (s == e) continue;                 // offS uniform -> safe skip
        for (int k = s + tid; k < e; k += 512) {
            int x = cw[k];
            float w = __int_as_float(x & 0xFFFFF000);
            int  cp = x & 0xFFF;
            lds_fadd(&val0[cp], w * val0[k]);
            lds_fadd(&val1[cp], w * val1[k]);
            lds_fadd(&nrm[cp],  w * nrm[k]);
        }
        __syncthreads();
    }

    // downward: in place; parent (level d-1) final before level d reads it
    for (int d = 1; d <= NLEV - 1; ++d) {
        int s = offS[d], e = offS[d + 1];
        if (s == e) continue;
        for (int k = s + tid; k < e; k += 512) {
            int x = cw[k];
            float w = __int_as_float(x & 0xFFFFF000);
            int  cp = x & 0xFFF;
            float u0 = val0[k], u1 = val1[k], un = nrm[k];
            val0[k] = fmaf(w, fmaf(-w, u0, val0[cp]), u0);
            val1[k] = fmaf(w, fmaf(-w, u1, val1[cp]), u1);
            nrm[k]  = fmaf(w, fmaf(-w, un, nrm[cp]),  un);
        }
        __syncthreads();
    }

    // epilogue: scattered b32 LDS reads, coalesced float4 stores, 2 channels
    float* o0 = out + ((size_t)(b * CC + c0)) * VV;
    float* o1 = o0 + VV;
    #pragma unroll
    for (int t = 0; t < 2; ++t) {
        int idx = tid + t * 512;
        int4 kk = kkR[t];
        float i0 = __fdividef(1.f, nrm[kk.x]);
        float i1 = __fdividef(1.f, nrm[kk.y]);
        float i2 = __fdividef(1.f, nrm[kk.z]);
        float i3 = __fdividef(1.f, nrm[kk.w]);
        float4 r0, r1;
        r0.x = val0[kk.x] * i0; r0.y = val0[kk.y] * i1;
        r0.z = val0[kk.z] * i2; r0.w = val0[kk.w] * i3;
        r1.x = val1[kk.x] * i0; r1.y = val1[kk.y] * i1;
        r1.z = val1[kk.z] * i2; r1.w = val1[kk.w] * i3;
        ((float4*)o0)[idx] = r0;
        ((float4*)o1)[idx] = r1;
    }
}

extern "C" void kernel_launch(void* const* d_in, const int* in_sizes, int n_in,
                              void* d_out, int out_size, void* d_ws, size_t ws_size,
                              hipStream_t stream) {
    const float* feat          = (const float*)d_in[0];
    const float* embed         = (const float*)d_in[1];
    const int*   sorted_index  = (const int*)d_in[2];
    const int*   sorted_parent = (const int*)d_in[3];
    const int*   node_level    = (const int*)d_in[4];
    float* out = (float*)d_out;

    char* ws = (char*)d_ws;
    const size_t A = (size_t)BB * VV * 4;     // 64 KB
    float* wsort = (float*)(ws);              // 64 KB
    int*   giInv = (int*)  (ws + A);          // 64 KB
    int2*  cpl   = (int2*) (ws + 2 * A);      // 128 KB
    int*   offs  = (int*)  (ws + 4 * A);      // 256 B

    prep_kernel<<<BB + BB * 64, 256, 0, stream>>>(
        embed, sorted_index, sorted_parent, node_level, wsort, giInv, cpl, offs);

    tree2_kernel<<<BB * CC / 2, 512, 0, stream>>>(
        feat, wsort, giInv, cpl, offs, out);
}